// Round 18
// baseline (123.715 us; speedup 1.0000x reference)
//
#include <hip/hip_runtime.h>
#include <hip/hip_bf16.h>

#define CIN    32
#define NPIX   4096   // 64*64 spatial positions
#define DIM    64     // attention channels
#define LOG2E  1.4426950408889634f

#if __has_builtin(__builtin_amdgcn_exp2f)
#define EXP2(x) __builtin_amdgcn_exp2f(x)
#else
#define EXP2(x) exp2f(x)
#endif

typedef float  f32x4  __attribute__((ext_vector_type(4)));
typedef float  f32x16 __attribute__((ext_vector_type(16)));
typedef short  s16x8  __attribute__((ext_vector_type(8)));   // 8 bf16 = one 32x32x16 A/B fragment

#define ZERO16 {0.f,0.f,0.f,0.f,0.f,0.f,0.f,0.f,0.f,0.f,0.f,0.f,0.f,0.f,0.f,0.f}

__device__ __forceinline__ f32x16 mfma32(s16x8 a, s16x8 b, f32x16 c) {
    return __builtin_amdgcn_mfma_f32_32x32x16_bf16(a, b, c, 0, 0, 0);
}

// ---------------------------------------------------------------------------
// Layouts (all per batch b):
//  Q: row-major (N, 64), PRE-SCALED by log2(e).
//  K: 32x32x16 A-frag order: [s(128)][kt(4)][h2(2)][key(32)][j(8)]
//  V: CONTIGUOUS-frag order of V^T: [s(128)][cht(2)][m(2)][hk(2)][ch'(32)][j(8)]
//  No softmax shift anywhere: scores' = s*log2e <= ~30, exp2 safe in f32/bf16.
// ---------------------------------------------------------------------------

// ---------------------------------------------------------------------------
// Kernel A v2: MFMA QKV projection (verified R14/R15/R17; ~5us). NO LDS/barriers.
// ---------------------------------------------------------------------------
__global__ __launch_bounds__(256) void qkv_proj(
    const float* __restrict__ x,
    const float* __restrict__ wq, const float* __restrict__ bq,
    const float* __restrict__ wk, const float* __restrict__ bk,
    const float* __restrict__ wv, const float* __restrict__ bv,
    __hip_bfloat16* __restrict__ qb, __hip_bfloat16* __restrict__ kb,
    __hip_bfloat16* __restrict__ vb)
{
    const int tid  = threadIdx.x;
    const int wid  = tid >> 6;          // wave 0..3
    const int lane = tid & 63;
    const int l31  = lane & 31;
    const int hl   = lane >> 5;
    const int b    = blockIdx.y;
    const int bx   = blockIdx.x;
    const int s    = bx * 4 + wid;      // 32-pixel tile (0..127)
    const int px   = s * 32 + l31;      // this lane's pixel

    s16x8 xhi[2], xlo[2];
    #pragma unroll
    for (int kt = 0; kt < 2; kt++) {
        union { s16x8 v; __hip_bfloat16 h8[8]; } uh, ul;
        #pragma unroll
        for (int j = 0; j < 8; j++) {
            const int c = kt * 16 + hl * 8 + j;
            const float xv = x[((size_t)b * CIN + c) * NPIX + px];
            const __hip_bfloat16 hi = __float2bfloat16(xv);
            uh.h8[j] = hi;
            ul.h8[j] = __float2bfloat16(xv - __bfloat162float(hi));
        }
        xhi[kt] = uh.v; xlo[kt] = ul.v;
    }

    auto do_mat = [&](const float* __restrict__ W, const float* __restrict__ B,
                      int which) {
        const float scale = (which == 0) ? LOG2E : 1.0f;
        s16x8 whi[2][2], wlo[2][2];
        #pragma unroll
        for (int t = 0; t < 2; t++)
            #pragma unroll
            for (int kt = 0; kt < 2; kt++) {
                const float* wp = W + (size_t)(t * 32 + l31) * CIN + kt * 16 + hl * 8;
                f32x4 a0 = *(const f32x4*)wp;
                f32x4 a1 = *(const f32x4*)(wp + 4);
                union { s16x8 v; __hip_bfloat16 h8[8]; } uh, ul;
                #pragma unroll
                for (int j = 0; j < 4; j++) {
                    const float v0 = a0[j] * scale, v1 = a1[j] * scale;
                    const __hip_bfloat16 h0 = __float2bfloat16(v0);
                    const __hip_bfloat16 h1 = __float2bfloat16(v1);
                    uh.h8[j] = h0; uh.h8[4 + j] = h1;
                    ul.h8[j]     = __float2bfloat16(v0 - __bfloat162float(h0));
                    ul.h8[4 + j] = __float2bfloat16(v1 - __bfloat162float(h1));
                }
                whi[t][kt] = uh.v; wlo[t][kt] = ul.v;
            }

        f32x16 acc0 = ZERO16, acc1 = ZERO16;
        if (which < 2) {
            #pragma unroll
            for (int kt = 0; kt < 2; kt++) {
                acc0 = mfma32(whi[0][kt], xhi[kt], acc0);
                acc1 = mfma32(whi[1][kt], xhi[kt], acc1);
                acc0 = mfma32(whi[0][kt], xlo[kt], acc0);
                acc1 = mfma32(whi[1][kt], xlo[kt], acc1);
                acc0 = mfma32(wlo[0][kt], xhi[kt], acc0);
                acc1 = mfma32(wlo[1][kt], xhi[kt], acc1);
            }
            #pragma unroll
            for (int t = 0; t < 2; t++) {
                const f32x16 acc = t ? acc1 : acc0;
                #pragma unroll
                for (int ig = 0; ig < 4; ig++) {
                    f32x4 b4 = *(const f32x4*)(B + t * 32 + ig * 8 + hl * 4);
                    union { unsigned long long u; __hip_bfloat16 h4[4]; } st;
                    #pragma unroll
                    for (int r = 0; r < 4; r++)
                        st.h4[r] = __float2bfloat16(acc[ig * 4 + r] + b4[r] * scale);
                    if (which == 0) {
                        const size_t off = ((size_t)b * NPIX + px) * DIM
                                         + t * 32 + ig * 8 + hl * 4;
                        *(unsigned long long*)(qb + off) = st.u;
                    } else {
                        const size_t off = (size_t)b * 262144
                            + ((size_t)(s * 4 + 2 * t + (ig >> 1)) * 64
                               + (ig & 1) * 32 + l31) * 8 + 4 * hl;
                        *(unsigned long long*)(kb + off) = st.u;
                    }
                }
            }
        } else {
            #pragma unroll
            for (int kt = 0; kt < 2; kt++) {
                acc0 = mfma32(xhi[kt], whi[0][kt], acc0);
                acc1 = mfma32(xhi[kt], whi[1][kt], acc1);
                acc0 = mfma32(xlo[kt], whi[0][kt], acc0);
                acc1 = mfma32(xlo[kt], whi[1][kt], acc1);
                acc0 = mfma32(xhi[kt], wlo[0][kt], acc0);
                acc1 = mfma32(xhi[kt], wlo[1][kt], acc1);
            }
            #pragma unroll
            for (int t = 0; t < 2; t++) {
                const f32x16 acc = t ? acc1 : acc0;
                const float bvv = B[t * 32 + l31];
                #pragma unroll
                for (int m = 0; m < 2; m++) {
                    union { s16x8 v; __hip_bfloat16 h8[8]; } st;
                    #pragma unroll
                    for (int e = 0; e < 8; e++)
                        st.h8[e] = __float2bfloat16(acc[m * 8 + e] + bvv);
                    const size_t off = (size_t)b * 262144
                        + ((size_t)(s * 4 + 2 * t + m) * 64 + hl * 32 + l31) * 8;
                    *(s16x8*)(vb + off) = st.v;
                }
            }
        }
    };

    do_mat(wq, bq, 0);
    do_mat(wk, bk, 1);
    do_mat(wv, bv, 2);
}

// ---------------------------------------------------------------------------
// Kernel B v16: RE-TEST TRUE 2 BLOCKS/CU NOW THAT SETPRIO IS GONE.
//   R17 confirmed setprio(1) was serializing co-resident waves (removal:
//   46.6 -> 41.8 us, combined util 58 -> 68%). All prior occupancy tests
//   (v8/v9) ran WITH setprio -- the overlap they were meant to create was
//   actively suppressed. v16 = v9 geometry (grid (8,64) = 512 blocks =
//   2/CU; 8 waves = 2 q-groups x 4 key-quarters; 1 tile/wave/phase; 32
//   phases; slot-w staging dbuf 64 KB; epilogue REDq ALIASED into staging)
//   with v15's lessons: NO setprio anywhere; single 4-deep S chain; PV
//   2-deep per accumulator. ~96 unified regs <= 128 @ (512,4) -- no spill
//   risk (v9 measured VGPR 64). Two independent blocks/CU have
//   uncorrelated barrier phases -> cross-block overlap of the ~32% idle.
// ---------------------------------------------------------------------------
__global__ __launch_bounds__(512, 4) void attn_fused(
    const __hip_bfloat16* __restrict__ qb,
    const __hip_bfloat16* __restrict__ kbf,
    const __hip_bfloat16* __restrict__ vbf,
    const float* __restrict__ wo, const float* __restrict__ bo,
    const float* __restrict__ x, float* __restrict__ y)
{
    __shared__ __align__(16) char sm[2][8][4096];   // 64 KB staging; epilogue aliases
    __shared__ float LRED2[3][2][32];               // row-sum partials 768 B

    float (*REDq)[2][64][33] = (float (*)[2][64][33])&sm[0][0][0]; // 50688 B alias

    const int tid  = threadIdx.x;
    const int w    = tid >> 6;          // wave 0..7
    const int g    = w >> 2;            // q-group (32 rows)
    const int kq   = w & 3;             // key quarter (1024 keys = 32 tiles)
    const int lane = tid & 63;
    const int q    = lane & 31;         // C/D column = q-row index
    const int hl   = lane >> 5;         // lane half
    const int b    = blockIdx.x;        // batch -> XCD affinity (lin%8 = b)
    const int row0 = blockIdx.y * 64 + g * 32;

    // Q B-frags (32x32x16): elem j at half hl -> dim kt*16 + hl*8 + j
    s16x8 qf[4];
    #pragma unroll
    for (int kt = 0; kt < 4; kt++)
        qf[kt] = *(const s16x8*)(qb + ((size_t)b * NPIX + row0 + q) * DIM
                                 + kt * 16 + hl * 8);

    f32x16 o0 = ZERO16, o1 = ZERO16;    // O^T[ch 0-31][q], O^T[ch 32-63][q]
    float lsacc = 0.f;                  // per-lane partial row-sum

    // staging: wave w stages slot w = kv(1)|quarter(2): kv = w>>2, qs = w&3.
    const char* stbase = ((w >> 2) ? (const char*)vbf : (const char*)kbf)
                       + (size_t)b * 524288
                       + (size_t)(w & 3) * 131072     // 32 tiles per quarter
                       + (size_t)lane * 16;
    char* std0 = &sm[0][w][lane * 16];
    char* std1 = &sm[1][w][lane * 16];

    // prologue: stage tile 0 into buf 0
    #pragma unroll
    for (int i = 0; i < 4; i++)
        *(f32x4*)(std0 + i * 1024) = *(const f32x4*)(stbase + i * 1024);
    __syncthreads();

    int cur = 0;
    for (int p = 0; p < 32; ++p) {
        // K fragments from current buffer (contiguous 1 KB frags: conflict-free)
        const char* Kl = sm[cur][kq];
        s16x8 kf[4];
        #pragma unroll
        for (int i = 0; i < 4; i++)
            kf[i] = *(const s16x8*)(Kl + i * 1024 + lane * 16);

        // issue next-phase staging loads early (full phase to land)
        const size_t srcoff = (size_t)((p < 31) ? p + 1 : 31) * 4096;
        f32x4 r0 = *(const f32x4*)(stbase + srcoff);
        f32x4 r1 = *(const f32x4*)(stbase + srcoff + 1024);
        f32x4 r2 = *(const f32x4*)(stbase + srcoff + 2048);
        f32x4 r3 = *(const f32x4*)(stbase + srcoff + 3072);

        // S^T: single 4-deep chain (NO setprio)
        f32x16 s = ZERO16;
        s = mfma32(kf[0], qf[0], s);
        s = mfma32(kf[1], qf[1], s);
        s = mfma32(kf[2], qf[2], s);
        s = mfma32(kf[3], qf[3], s);

        // P^T = exp2(S^T) -> bf16 B-frags; VALU row-sum
        union { s16x8 v; __hip_bfloat16 h8[8]; } p0, p1;
        #pragma unroll
        for (int j = 0; j < 8; j++) {
            float e0 = EXP2(s[j]);
            float e1 = EXP2(s[8 + j]);
            lsacc += e0 + e1;
            p0.h8[j] = __float2bfloat16(e0);
            p1.h8[j] = __float2bfloat16(e1);
        }

        // V fragments
        const char* Vl = sm[cur][4 + kq];
        s16x8 vv[4];
        #pragma unroll
        for (int i = 0; i < 4; i++)
            vv[i] = *(const s16x8*)(Vl + i * 1024 + lane * 16);

        // O^T += V^T P^T  (two independent 2-deep chains; NO setprio)
        o0 = mfma32(vv[0], p0.v, o0);
        o1 = mfma32(vv[2], p0.v, o1);
        o0 = mfma32(vv[1], p1.v, o0);
        o1 = mfma32(vv[3], p1.v, o1);

        // write staged tile into the other buffer, then phase barrier
        char* dst = cur ? std0 : std1;
        *(f32x4*)(dst)        = r0;
        *(f32x4*)(dst + 1024) = r1;
        *(f32x4*)(dst + 2048) = r2;
        *(f32x4*)(dst + 3072) = r3;
        __syncthreads();
        cur ^= 1;
    }

    // cross-half row-sum combine (both lane-halves hold same q, disjoint keys)
    lsacc += __shfl_xor(lsacc, 32, 64);

    // ---- combine the four key-quarters per q-group (REDq aliases staging) ----
    if (kq != 0) {
        #pragma unroll
        for (int i = 0; i < 16; i++) {
            const int rr = (i & 3) + 8 * (i >> 2) + 4 * hl;
            REDq[kq - 1][g][rr][q]      = o0[i];
            REDq[kq - 1][g][32 + rr][q] = o1[i];
        }
        if (hl == 0) LRED2[kq - 1][g][q] = lsacc;
    }
    __syncthreads();

    if (kq == 0) {
        #pragma unroll
        for (int sl = 0; sl < 3; sl++) {
            lsacc += LRED2[sl][g][q];
            #pragma unroll
            for (int i = 0; i < 16; i++) {
                const int rr = (i & 3) + 8 * (i >> 2) + 4 * hl;
                o0[i] += REDq[sl][g][rr][q];
                o1[i] += REDq[sl][g][32 + rr][q];
            }
        }
        const float inv = 1.0f / lsacc;

        // normalized O^T -> B-frags per 16-ch group (direct from registers)
        s16x8 pbo[4];
        #pragma unroll
        for (int gg = 0; gg < 4; gg++) {
            union { s16x8 v; __hip_bfloat16 h8[8]; } pk;
            #pragma unroll
            for (int j = 0; j < 8; j++) {
                const float vv2 = (gg < 2) ? o0[(gg & 1) * 8 + j] : o1[(gg & 1) * 8 + j];
                pk.h8[j] = __float2bfloat16(vv2 * inv);
            }
            pbo[gg] = pk.v;
        }

        // wo A-frags with the key/ch relabeling mu(gg,hl,j)
        s16x8 aw[4];
        #pragma unroll
        for (int gg = 0; gg < 4; gg++) {
            f32x4 w0 = *(const f32x4*)(wo + (size_t)q * DIM + gg * 16 + hl * 4);
            f32x4 w1 = *(const f32x4*)(wo + (size_t)q * DIM + gg * 16 + 8 + hl * 4);
            union { s16x8 v; __hip_bfloat16 h8[8]; } wf;
            #pragma unroll
            for (int j = 0; j < 4; j++) {
                wf.h8[j]     = __float2bfloat16(w0[j]);
                wf.h8[4 + j] = __float2bfloat16(w1[j]);
            }
            aw[gg] = wf.v;
        }

        // Y^T[out][q] = wo x ONorm^T  (single 32x32 tile, K=64 over 4 mfmas)
        f32x16 d = ZERO16;
        #pragma unroll
        for (int gg = 0; gg < 4; gg++)
            d = mfma32(aw[gg], pbo[gg], d);

        // bias + residual + store y (B, 32, 4096) fp32
        #pragma unroll
        for (int i = 0; i < 16; i++) {
            const int out = (i & 3) + 8 * (i >> 2) + 4 * hl;
            const int row = row0 + q;
            const size_t xi = ((size_t)b * CIN + out) * NPIX + row;
            y[xi] = d[i] + bo[out] + x[xi];
        }
    }
}

// ---------------------------------------------------------------------------
extern "C" void kernel_launch(void* const* d_in, const int* in_sizes, int n_in,
                              void* d_out, int out_size, void* d_ws, size_t ws_size,
                              hipStream_t stream)
{
    const float* x  = (const float*)d_in[0];
    const float* wq = (const float*)d_in[1];
    const float* bq = (const float*)d_in[2];
    const float* wk = (const float*)d_in[3];
    const float* bk = (const float*)d_in[4];
    const float* wv = (const float*)d_in[5];
    const float* bv = (const float*)d_in[6];
    const float* wo = (const float*)d_in[7];
    const float* bo = (const float*)d_in[8];
    float* y = (float*)d_out;

    // workspace: qb 4MB (row-major, log2e-scaled) | kb 4MB | vb 4MB (frag orders)
    char* ws = (char*)d_ws;
    __hip_bfloat16* qb = (__hip_bfloat16*)(ws);
    __hip_bfloat16* kb = (__hip_bfloat16*)(ws + (4u << 20));
    __hip_bfloat16* vb = (__hip_bfloat16*)(ws + (8u << 20));

    qkv_proj<<<dim3(32, 8), dim3(256), 0, stream>>>(x, wq, bq, wk, bk, wv, bv, qb, kb, vb);
    attn_fused<<<dim3(8, 64), dim3(512), 0, stream>>>(qb, kb, vb, wo, bo, x, y);
}

// Round 19
// 119.077 us; speedup vs baseline: 1.0389x; 1.0389x over previous
//
#include <hip/hip_runtime.h>
#include <hip/hip_bf16.h>

#define CIN    32
#define NPIX   4096   // 64*64 spatial positions
#define DIM    64     // attention channels
#define LOG2E  1.4426950408889634f

#if __has_builtin(__builtin_amdgcn_exp2f)
#define EXP2(x) __builtin_amdgcn_exp2f(x)
#else
#define EXP2(x) exp2f(x)
#endif

typedef float  f32x4  __attribute__((ext_vector_type(4)));
typedef float  f32x16 __attribute__((ext_vector_type(16)));
typedef short  s16x8  __attribute__((ext_vector_type(8)));   // 8 bf16 = one 32x32x16 A/B fragment

#define ZERO16 {0.f,0.f,0.f,0.f,0.f,0.f,0.f,0.f,0.f,0.f,0.f,0.f,0.f,0.f,0.f,0.f}

__device__ __forceinline__ f32x16 mfma32(s16x8 a, s16x8 b, f32x16 c) {
    return __builtin_amdgcn_mfma_f32_32x32x16_bf16(a, b, c, 0, 0, 0);
}

// ---------------------------------------------------------------------------
// Layouts (all per batch b):
//  Q: row-major (N, 64), PRE-SCALED by log2(e).
//  K: 32x32x16 A-frag order: [s(128)][kt(4)][h2(2)][key(32)][j(8)]
//  V: CONTIGUOUS-frag order of V^T: [s(128)][cht(2)][m(2)][hk(2)][ch'(32)][j(8)]
//  No softmax shift anywhere: scores' = s*log2e <= ~30, exp2 safe in f32/bf16.
// ---------------------------------------------------------------------------

// ---------------------------------------------------------------------------
// Kernel A v2: MFMA QKV projection (verified R14/R15/R17; ~5us). NO LDS/barriers.
// ---------------------------------------------------------------------------
__global__ __launch_bounds__(256) void qkv_proj(
    const float* __restrict__ x,
    const float* __restrict__ wq, const float* __restrict__ bq,
    const float* __restrict__ wk, const float* __restrict__ bk,
    const float* __restrict__ wv, const float* __restrict__ bv,
    __hip_bfloat16* __restrict__ qb, __hip_bfloat16* __restrict__ kb,
    __hip_bfloat16* __restrict__ vb)
{
    const int tid  = threadIdx.x;
    const int wid  = tid >> 6;          // wave 0..3
    const int lane = tid & 63;
    const int l31  = lane & 31;
    const int hl   = lane >> 5;
    const int b    = blockIdx.y;
    const int bx   = blockIdx.x;
    const int s    = bx * 4 + wid;      // 32-pixel tile (0..127)
    const int px   = s * 32 + l31;      // this lane's pixel

    s16x8 xhi[2], xlo[2];
    #pragma unroll
    for (int kt = 0; kt < 2; kt++) {
        union { s16x8 v; __hip_bfloat16 h8[8]; } uh, ul;
        #pragma unroll
        for (int j = 0; j < 8; j++) {
            const int c = kt * 16 + hl * 8 + j;
            const float xv = x[((size_t)b * CIN + c) * NPIX + px];
            const __hip_bfloat16 hi = __float2bfloat16(xv);
            uh.h8[j] = hi;
            ul.h8[j] = __float2bfloat16(xv - __bfloat162float(hi));
        }
        xhi[kt] = uh.v; xlo[kt] = ul.v;
    }

    auto do_mat = [&](const float* __restrict__ W, const float* __restrict__ B,
                      int which) {
        const float scale = (which == 0) ? LOG2E : 1.0f;
        s16x8 whi[2][2], wlo[2][2];
        #pragma unroll
        for (int t = 0; t < 2; t++)
            #pragma unroll
            for (int kt = 0; kt < 2; kt++) {
                const float* wp = W + (size_t)(t * 32 + l31) * CIN + kt * 16 + hl * 8;
                f32x4 a0 = *(const f32x4*)wp;
                f32x4 a1 = *(const f32x4*)(wp + 4);
                union { s16x8 v; __hip_bfloat16 h8[8]; } uh, ul;
                #pragma unroll
                for (int j = 0; j < 4; j++) {
                    const float v0 = a0[j] * scale, v1 = a1[j] * scale;
                    const __hip_bfloat16 h0 = __float2bfloat16(v0);
                    const __hip_bfloat16 h1 = __float2bfloat16(v1);
                    uh.h8[j] = h0; uh.h8[4 + j] = h1;
                    ul.h8[j]     = __float2bfloat16(v0 - __bfloat162float(h0));
                    ul.h8[4 + j] = __float2bfloat16(v1 - __bfloat162float(h1));
                }
                whi[t][kt] = uh.v; wlo[t][kt] = ul.v;
            }

        f32x16 acc0 = ZERO16, acc1 = ZERO16;
        if (which < 2) {
            #pragma unroll
            for (int kt = 0; kt < 2; kt++) {
                acc0 = mfma32(whi[0][kt], xhi[kt], acc0);
                acc1 = mfma32(whi[1][kt], xhi[kt], acc1);
                acc0 = mfma32(whi[0][kt], xlo[kt], acc0);
                acc1 = mfma32(whi[1][kt], xlo[kt], acc1);
                acc0 = mfma32(wlo[0][kt], xhi[kt], acc0);
                acc1 = mfma32(wlo[1][kt], xhi[kt], acc1);
            }
            #pragma unroll
            for (int t = 0; t < 2; t++) {
                const f32x16 acc = t ? acc1 : acc0;
                #pragma unroll
                for (int ig = 0; ig < 4; ig++) {
                    f32x4 b4 = *(const f32x4*)(B + t * 32 + ig * 8 + hl * 4);
                    union { unsigned long long u; __hip_bfloat16 h4[4]; } st;
                    #pragma unroll
                    for (int r = 0; r < 4; r++)
                        st.h4[r] = __float2bfloat16(acc[ig * 4 + r] + b4[r] * scale);
                    if (which == 0) {
                        const size_t off = ((size_t)b * NPIX + px) * DIM
                                         + t * 32 + ig * 8 + hl * 4;
                        *(unsigned long long*)(qb + off) = st.u;
                    } else {
                        const size_t off = (size_t)b * 262144
                            + ((size_t)(s * 4 + 2 * t + (ig >> 1)) * 64
                               + (ig & 1) * 32 + l31) * 8 + 4 * hl;
                        *(unsigned long long*)(kb + off) = st.u;
                    }
                }
            }
        } else {
            #pragma unroll
            for (int kt = 0; kt < 2; kt++) {
                acc0 = mfma32(xhi[kt], whi[0][kt], acc0);
                acc1 = mfma32(xhi[kt], whi[1][kt], acc1);
                acc0 = mfma32(xlo[kt], whi[0][kt], acc0);
                acc1 = mfma32(xlo[kt], whi[1][kt], acc1);
                acc0 = mfma32(xhi[kt], wlo[0][kt], acc0);
                acc1 = mfma32(xhi[kt], wlo[1][kt], acc1);
            }
            #pragma unroll
            for (int t = 0; t < 2; t++) {
                const f32x16 acc = t ? acc1 : acc0;
                const float bvv = B[t * 32 + l31];
                #pragma unroll
                for (int m = 0; m < 2; m++) {
                    union { s16x8 v; __hip_bfloat16 h8[8]; } st;
                    #pragma unroll
                    for (int e = 0; e < 8; e++)
                        st.h8[e] = __float2bfloat16(acc[m * 8 + e] + bvv);
                    const size_t off = (size_t)b * 262144
                        + ((size_t)(s * 4 + 2 * t + m) * 64 + hl * 32 + l31) * 8;
                    *(s16x8*)(vb + off) = st.v;
                }
            }
        }
    };

    do_mat(wq, bq, 0);
    do_mat(wk, bk, 1);
    do_mat(wv, bv, 2);
}

// ---------------------------------------------------------------------------
// Kernel B v17: v15 base (best: 41.8us, no setprio, split PV accumulators)
//   + V BYPASSES LDS (single-variable change).
//   v15's hidden pipe: LDS ~160 KB/CU/phase (~40-60% busy) -- the largest.
//   Prior LDS cuts (v10/v14) were tested WITH setprio (lockstep convoy made
//   LDS off-critical-path); with interleaving restored, the cut can show.
//   V frags are contiguous 1 KB blocks: read direct from global at phase
//   top (consumed after S+exp2, ~600cy slack covers L2; 4 waves of the same
//   half read identical addresses within a phase -> L1 hits, 8 KB << 32 KB).
//   LDS/CU/phase 160 -> 80 KB. K staging spread over all 8 waves (2 KB ea).
//   LDS static 99.8 -> ~67 KB. FETCH unchanged (V from L1/L2, not HBM).
// ---------------------------------------------------------------------------
__global__ __launch_bounds__(512, 2) void attn_fused(
    const __hip_bfloat16* __restrict__ qb,
    const __hip_bfloat16* __restrict__ kbf,
    const __hip_bfloat16* __restrict__ vbf,
    const float* __restrict__ wo, const float* __restrict__ bo,
    const float* __restrict__ x, float* __restrict__ y)
{
    __shared__ __align__(16) char  smK[2][4][4096];   // K staging dbuf 32 KB
    __shared__ __align__(16) float REDx[4][64][33];   // epilogue partials 33792 B
    __shared__ float LRED2[4][32];                    // row-sums

    const int tid  = threadIdx.x;
    const int w    = tid >> 6;          // wave 0..7
    const int g    = w >> 1;            // q-group (32 rows)
    const int h    = w & 1;             // key half (2048 keys = 32 phases x 2 tiles)
    const int lane = tid & 63;
    const int q    = lane & 31;         // C/D column = q-row index
    const int hl   = lane >> 5;         // lane half
    const int b    = blockIdx.x;        // batch -> XCD affinity (lin%8 = b)
    const int row0 = blockIdx.y * 128 + g * 32;

    // Q B-frags (32x32x16): elem j at half hl -> dim kt*16 + hl*8 + j
    s16x8 qf[4];
    #pragma unroll
    for (int kt = 0; kt < 4; kt++)
        qf[kt] = *(const s16x8*)(qb + ((size_t)b * NPIX + row0 + q) * DIM
                                 + kt * 16 + hl * 8);

    f32x16 o0a = ZERO16, o0b = ZERO16;  // O^T[ch 0-31][q] split accumulators
    f32x16 o1a = ZERO16, o1b = ZERO16;  // O^T[ch 32-63][q] split accumulators
    float lsacc = 0.f;                  // per-lane partial row-sum

    // K staging: wave w stages 2 KB = piece (w&1) of slot (w>>1).
    //   slot s = khalf*2 + sub; addr advances 8192/phase (2 tiles per half).
    const char* kst = (const char*)kbf + (size_t)b * 524288
                    + (size_t)((w >> 1) >> 1) * 262144      // key half of slot
                    + (size_t)((w >> 1) & 1) * 4096         // sub-tile
                    + (size_t)(w & 1) * 2048 + (size_t)lane * 16;
    char* std0 = &smK[0][w >> 1][(w & 1) * 2048 + lane * 16];
    char* std1 = &smK[1][w >> 1][(w & 1) * 2048 + lane * 16];

    // V direct-global base for this wave's key half (contiguous 1 KB frags)
    const char* vbase = (const char*)vbf + (size_t)b * 524288
                      + (size_t)h * 262144 + (size_t)lane * 16;

    // prologue: stage K phase 0 into buf 0
    *(f32x4*)(std0)        = *(const f32x4*)(kst);
    *(f32x4*)(std0 + 1024) = *(const f32x4*)(kst + 1024);
    __syncthreads();

    int cur = 0;
    for (int p = 0; p < 32; ++p) {
        // V tiles for phase p: direct global (consumed after S+exp2 -- slack;
        // 4 waves per half hit the same lines -> L1)
        const char* vp = vbase + (size_t)p * 8192;
        s16x8 vv0[4], vv1[4];
        #pragma unroll
        for (int i = 0; i < 4; i++) {
            vv0[i] = *(const s16x8*)(vp + i * 1024);
            vv1[i] = *(const s16x8*)(vp + 4096 + i * 1024);
        }

        // K fragments from current LDS buffer (contiguous: conflict-free)
        const char* K0 = smK[cur][h * 2 + 0];
        const char* K1 = smK[cur][h * 2 + 1];
        s16x8 kf0[4], kf1[4];
        #pragma unroll
        for (int i = 0; i < 4; i++) {
            kf0[i] = *(const s16x8*)(K0 + i * 1024 + lane * 16);
            kf1[i] = *(const s16x8*)(K1 + i * 1024 + lane * 16);
        }

        // stage K for phase p+1: issue loads early
        const size_t so = (size_t)((p < 31) ? p + 1 : 31) * 8192;
        f32x4 r0 = *(const f32x4*)(kst + so);
        f32x4 r1 = *(const f32x4*)(kst + so + 1024);

        // S^T per tile: two independent 4-deep chains (NO setprio)
        f32x16 s0 = ZERO16, s1 = ZERO16;
        s0 = mfma32(kf0[0], qf[0], s0);
        s1 = mfma32(kf1[0], qf[0], s1);
        s0 = mfma32(kf0[1], qf[1], s0);
        s1 = mfma32(kf1[1], qf[1], s1);
        s0 = mfma32(kf0[2], qf[2], s0);
        s1 = mfma32(kf1[2], qf[2], s1);
        s0 = mfma32(kf0[3], qf[3], s0);
        s1 = mfma32(kf1[3], qf[3], s1);

        // P^T = exp2(S^T) -> bf16 B-frags; VALU row-sum
        union { s16x8 v; __hip_bfloat16 h8[8]; } p00, p01, p10, p11;
        #pragma unroll
        for (int r = 0; r < 16; r++) { s0[r] = EXP2(s0[r]); lsacc += s0[r]; }
        #pragma unroll
        for (int j = 0; j < 8; j++) {
            p00.h8[j] = __float2bfloat16(s0[j]);
            p01.h8[j] = __float2bfloat16(s0[8 + j]);
        }
        #pragma unroll
        for (int r = 0; r < 16; r++) { s1[r] = EXP2(s1[r]); lsacc += s1[r]; }
        #pragma unroll
        for (int j = 0; j < 8; j++) {
            p10.h8[j] = __float2bfloat16(s1[j]);
            p11.h8[j] = __float2bfloat16(s1[8 + j]);
        }

        // O^T += V^T P^T  (8 MFMAs, four 2-deep accum chains; NO setprio)
        o0a = mfma32(vv0[0], p00.v, o0a);
        o1a = mfma32(vv0[2], p00.v, o1a);
        o0a = mfma32(vv0[1], p01.v, o0a);
        o1a = mfma32(vv0[3], p01.v, o1a);
        o0b = mfma32(vv1[0], p10.v, o0b);
        o1b = mfma32(vv1[2], p10.v, o1b);
        o0b = mfma32(vv1[1], p11.v, o0b);
        o1b = mfma32(vv1[3], p11.v, o1b);

        // write staged K into the other buffer, then phase barrier
        char* dst = cur ? std0 : std1;
        *(f32x4*)(dst)        = r0;
        *(f32x4*)(dst + 1024) = r1;
        __syncthreads();
        cur ^= 1;
    }

    // merge split accumulators
    f32x16 o0 = o0a + o0b;
    f32x16 o1 = o1a + o1b;

    // cross-half row-sum combine (both lane-halves hold same q, disjoint keys)
    lsacc += __shfl_xor(lsacc, 32, 64);

    // ---- combine the two key-halves per q-group ----
    if (h == 1) {
        #pragma unroll
        for (int i = 0; i < 16; i++) {
            const int rr = (i & 3) + 8 * (i >> 2) + 4 * hl;
            REDx[g][rr][q]      = o0[i];
            REDx[g][32 + rr][q] = o1[i];
        }
        if (hl == 0) LRED2[g][q] = lsacc;
    }
    __syncthreads();

    if (h == 0) {
        const float lsum = lsacc + LRED2[g][q];
        #pragma unroll
        for (int i = 0; i < 16; i++) {
            const int rr = (i & 3) + 8 * (i >> 2) + 4 * hl;
            o0[i] += REDx[g][rr][q];
            o1[i] += REDx[g][32 + rr][q];
        }
        const float inv = 1.0f / lsum;

        // normalized O^T -> B-frags per 16-ch group (direct from registers)
        s16x8 pbo[4];
        #pragma unroll
        for (int gg = 0; gg < 4; gg++) {
            union { s16x8 v; __hip_bfloat16 h8[8]; } pk;
            #pragma unroll
            for (int j = 0; j < 8; j++) {
                const float vv2 = (gg < 2) ? o0[(gg & 1) * 8 + j] : o1[(gg & 1) * 8 + j];
                pk.h8[j] = __float2bfloat16(vv2 * inv);
            }
            pbo[gg] = pk.v;
        }

        // wo A-frags with the key/ch relabeling mu(gg,hl,j)
        s16x8 aw[4];
        #pragma unroll
        for (int gg = 0; gg < 4; gg++) {
            f32x4 w0 = *(const f32x4*)(wo + (size_t)q * DIM + gg * 16 + hl * 4);
            f32x4 w1 = *(const f32x4*)(wo + (size_t)q * DIM + gg * 16 + 8 + hl * 4);
            union { s16x8 v; __hip_bfloat16 h8[8]; } wf;
            #pragma unroll
            for (int j = 0; j < 4; j++) {
                wf.h8[j]     = __float2bfloat16(w0[j]);
                wf.h8[4 + j] = __float2bfloat16(w1[j]);
            }
            aw[gg] = wf.v;
        }

        // Y^T[out][q] = wo x ONorm^T  (single 32x32 tile, K=64 over 4 mfmas)
        f32x16 d = ZERO16;
        #pragma unroll
        for (int gg = 0; gg < 4; gg++)
            d = mfma32(aw[gg], pbo[gg], d);

        // bias + residual + store y (B, 32, 4096) fp32
        #pragma unroll
        for (int i = 0; i < 16; i++) {
            const int out = (i & 3) + 8 * (i >> 2) + 4 * hl;
            const int row = row0 + q;
            const size_t xi = ((size_t)b * CIN + out) * NPIX + row;
            y[xi] = d[i] + bo[out] + x[xi];
        }
    }
}

// ---------------------------------------------------------------------------
extern "C" void kernel_launch(void* const* d_in, const int* in_sizes, int n_in,
                              void* d_out, int out_size, void* d_ws, size_t ws_size,
                              hipStream_t stream)
{
    const float* x  = (const float*)d_in[0];
    const float* wq = (const float*)d_in[1];
    const float* bq = (const float*)d_in[2];
    const float* wk = (const float*)d_in[3];
    const float* bk = (const float*)d_in[4];
    const float* wv = (const float*)d_in[5];
    const float* bv = (const float*)d_in[6];
    const float* wo = (const float*)d_in[7];
    const float* bo = (const float*)d_in[8];
    float* y = (float*)d_out;

    // workspace: qb 4MB (row-major, log2e-scaled) | kb 4MB | vb 4MB (frag orders)
    char* ws = (char*)d_ws;
    __hip_bfloat16* qb = (__hip_bfloat16*)(ws);
    __hip_bfloat16* kb = (__hip_bfloat16*)(ws + (4u << 20));
    __hip_bfloat16* vb = (__hip_bfloat16*)(ws + (8u << 20));

    qkv_proj<<<dim3(32, 8), dim3(256), 0, stream>>>(x, wq, bq, wk, bk, wv, bv, qb, kb, vb);
    attn_fused<<<dim3(8, 32), dim3(512), 0, stream>>>(qb, kb, vb, wo, bo, x, y);
}